// Round 13
// baseline (134.668 us; speedup 1.0000x reference)
//
#include <hip/hip_runtime.h>
#include <hip/hip_bf16.h>
#include <stdint.h>

// Sizes (fixed): B=4096, A=768, V=2048, H=512, F=1024, ND=16, NC=2, NE=8, NL=3

typedef __attribute__((ext_vector_type(8))) short bf16x8;
typedef __attribute__((ext_vector_type(4))) float f32x4;

__device__ inline short f2b(float f) {
  union { float f; uint32_t u; } a; a.f = f;
  uint32_t r = a.u + 0x7fffu + ((a.u >> 16) & 1u);   // RNE
  return (short)(r >> 16);
}
__device__ inline float b2f(short s) {
  union { uint32_t u; float f; } a; a.u = ((uint32_t)(uint16_t)s) << 16;
  return a.f;
}
__device__ inline void gload_lds16(const void* g, void* l) {
  __builtin_amdgcn_global_load_lds(
      (const __attribute__((address_space(1))) uint32_t*)g,
      (__attribute__((address_space(3))) uint32_t*)l, 16, 0, 0);
}
template<int N> __device__ __forceinline__ void waitv() {
  asm volatile("s_waitcnt vmcnt(%0)" :: "n"(N) : "memory");
}

// 64x64 f32->bf16 transpose tile via LDS scratch (needs >= 64*66 shorts).
__device__ __forceinline__
void transpose_tile(const float* __restrict__ in, short* __restrict__ out,
                    int N, int ldout, int n0, int k0, short* scratch) {
  short (*t)[66] = (short(*)[66])scratch;
  const int tid = threadIdx.x;
#pragma unroll
  for (int p = 0; p < 4; ++p) {
    const int item = p * 256 + tid;
    const int row = item >> 4, c4 = (item & 15) << 2;
    float4 v = *(const float4*)(in + (long)(k0 + row) * N + n0 + c4);
    short4 o; o.x = f2b(v.x); o.y = f2b(v.y); o.z = f2b(v.z); o.w = f2b(v.w);
    *(short4*)&t[row][c4] = o;
  }
  __syncthreads();
#pragma unroll
  for (int p = 0; p < 4; ++p) {
    const int item = p * 256 + tid;
    const int kg4 = item & 15, n = item >> 4;
    short4 o;
    o.x = t[4 * kg4 + 0][n]; o.y = t[4 * kg4 + 1][n];
    o.z = t[4 * kg4 + 2][n]; o.w = t[4 * kg4 + 3][n];
    *(short4*)(out + (long)(n0 + n) * ldout + k0 + 4 * kg4) = o;
  }
}

// ---------------- prep kernel: enc-stage deps only ----------------
// [0,96) Wa  [96,352) Wv  [352,864) Wproj  [864,1376) Watt_rm
// [1376,2144) audio conv  [2144,4192) video conv
__global__ __launch_bounds__(256)
void prep_k(const float* __restrict__ Wa, const float* __restrict__ Wv,
            const float* __restrict__ Wproj,
            const float* __restrict__ Pa, const float* __restrict__ Cva,
            const float* __restrict__ Cav, const float* __restrict__ Pv,
            const float* __restrict__ audio, const float* __restrict__ video,
            short* __restrict__ WaT, short* __restrict__ WvT,
            short* __restrict__ WprojT, short* __restrict__ Watt,
            short* __restrict__ a_bf, short* __restrict__ v_bf) {
  __shared__ short t[64 * 66];
  int b = blockIdx.x;
  const int tid = threadIdx.x;

  if (b >= 1376) {                    // input conversions, 4096 elems/block
    const float* in; short* out;
    if (b < 2144) { b -= 1376; in = audio; out = a_bf; }
    else          { b -= 2144; in = video; out = v_bf; }
    const long base_ = (long)b * 4096;
#pragma unroll
    for (int p = 0; p < 4; ++p) {
      const long i = base_ + ((p * 256 + tid) << 2);
      float4 v = *(const float4*)(in + i);
      short4 o; o.x = f2b(v.x); o.y = f2b(v.y); o.z = f2b(v.z); o.w = f2b(v.w);
      *(short4*)(out + i) = o;
    }
    return;
  }
  if (b >= 864) {                     // Watt_rm quadrants, 4 rows/block
    b -= 864;
    const int q = b >> 7, r4 = (b & 127) << 2;
    const float* src; int rowoff, coloff;
    if (q == 0)      { src = Pa;  rowoff = 0;   coloff = 0; }
    else if (q == 1) { src = Cav; rowoff = 0;   coloff = 1024; }
    else if (q == 2) { src = Cva; rowoff = 512; coloff = 0; }
    else             { src = Pv;  rowoff = 512; coloff = 1024; }
#pragma unroll
    for (int p = 0; p < 4; ++p) {
      const int item = p * 256 + tid;
      const int h = r4 + (item >> 8), j = (item & 255) << 2;
      float4 v = *(const float4*)(src + (long)h * 1024 + j);
      short4 o; o.x = f2b(v.x); o.y = f2b(v.y); o.z = f2b(v.z); o.w = f2b(v.w);
      *(short4*)(Watt + (long)(rowoff + h) * 2048 + coloff + j) = o;
    }
    return;
  }
  const float* in; short* out; int N, ldout, nnb;
  if (b < 96)       { in = Wa;    out = WaT;    N = 512;  ldout = 768;  nnb = 8; }
  else if (b < 352) { b -= 96;  in = Wv;    out = WvT;    N = 512;  ldout = 2048; nnb = 8; }
  else              { b -= 352; in = Wproj; out = WprojT; N = 1024; ldout = 2048; nnb = 16; }
  transpose_tile(in, out, N, ldout, (b % nnb) << 6, (b / nnb) << 6, t);
}

// ---------------- GEMM body: depth-2 prefetch + T2 XOR swizzle -------------
// C = A(MxK, bf16) * BT(NxK, bf16)^T. 4 waves (2x2); BK=64; 16x16x32 MFMA.
// 3 LDS buffers; per step: barrier / stage(t+2) / vmcnt(2S) / barrier / MFMA(t).
// Swizzle (rule #21): linear LDS dest; global source col-group pre-permuted
// (c8 = (tid&7) ^ (row&7)); reads XOR the same way.
template<int BM, int BN, bool RELU, bool HASF32>
__device__ __forceinline__
void gemm_body(const short* __restrict__ A, const short* __restrict__ BT,
               const float* __restrict__ bias,
               short* __restrict__ Cb, int ldcb,
               float* __restrict__ Cf, int ldcf,
               int K, int lda, int ldbt, int m0, int n0,
               short* lds) {
  constexpr int MR = BM / 32, NR = BN / 32;
  constexpr int S = MR + NR;                 // gload_lds per wave per tile
  constexpr int BUF = (BM + BN) * 64;        // shorts per buffer
  const int tid = threadIdx.x;
  const int w = tid >> 6, l = tid & 63;
  const int wr = w >> 1, wc = w & 1;
  const int lr = l & 15, lk = (l >> 4) << 3;

  f32x4 acc[MR][NR];
#pragma unroll
  for (int m = 0; m < MR; ++m)
#pragma unroll
    for (int n = 0; n < NR; ++n) acc[m][n] = (f32x4)0.f;

  const int r_ = tid >> 3;            // 0..31
  const int kc_ = (((tid & 7) ^ (r_ & 7)) << 3);   // swizzled source col-group
  const short* Arow = A + (long)(m0 + r_) * lda + kc_;
  const short* Brow = BT + (long)(n0 + r_) * ldbt + kc_;
  const int nk = K >> 6;

  auto stage = [&](int t, int buf) {
    const int kt = t << 6;
    char* sA = (char*)(lds + buf * BUF);
    char* sB = sA + BM * 128;
#pragma unroll
    for (int i = 0; i < MR; ++i)
      gload_lds16(Arow + (long)i * 32 * lda + kt, sA + i * 4096 + w * 1024);
#pragma unroll
    for (int i = 0; i < NR; ++i)
      gload_lds16(Brow + (long)i * 32 * ldbt + kt, sB + i * 4096 + w * 1024);
  };

  stage(0, 0);
  if (nk > 1) stage(1, 1);
  int cur = 0;
  for (int t = 0; t < nk; ++t) {
    __builtin_amdgcn_s_barrier();
    __builtin_amdgcn_sched_barrier(0);
    if (t + 2 < nk) {
      int nxt = cur + 2; if (nxt >= 3) nxt -= 3;
      stage(t + 2, nxt);
      waitv<2 * S>();
    } else if (t + 1 < nk) {
      waitv<S>();
    } else {
      waitv<0>();
    }
    __builtin_amdgcn_s_barrier();
    __builtin_amdgcn_sched_barrier(0);
    const short* sA = lds + cur * BUF;
    const short* sB = sA + BM * 64;
#pragma unroll
    for (int kk = 0; kk < 64; kk += 32) {
      const int cb = (kk + lk) >> 3;
      bf16x8 a[MR], b[NR];
#pragma unroll
      for (int m = 0; m < MR; ++m) {
        const int ra = wr * (BM / 2) + m * 16 + lr;
        a[m] = *(const bf16x8*)&sA[ra * 64 + ((cb ^ (ra & 7)) << 3)];
      }
#pragma unroll
      for (int n = 0; n < NR; ++n) {
        const int rb = wc * (BN / 2) + n * 16 + lr;
        b[n] = *(const bf16x8*)&sB[rb * 64 + ((cb ^ (rb & 7)) << 3)];
      }
#pragma unroll
      for (int m = 0; m < MR; ++m)
#pragma unroll
        for (int n = 0; n < NR; ++n)
          acc[m][n] = __builtin_amdgcn_mfma_f32_16x16x32_bf16(a[m], b[n], acc[m][n], 0, 0, 0);
    }
    __builtin_amdgcn_sched_barrier(0);
    cur = (cur == 2) ? 0 : cur + 1;
  }

  const int lrow = (l >> 4) << 2;
#pragma unroll
  for (int n = 0; n < NR; ++n) {
    const int col = n0 + wc * (BN / 2) + n * 16 + lr;
    const float bz = bias ? bias[col] : 0.f;
#pragma unroll
    for (int m = 0; m < MR; ++m) {
      const int rowb = m0 + wr * (BM / 2) + m * 16 + lrow;
#pragma unroll
      for (int i = 0; i < 4; ++i) {
        float v = acc[m][n][i] + bz;
        if (RELU) v = fmaxf(v, 0.f);
        Cb[(long)(rowb + i) * ldcb + col] = f2b(v);
        if (HASF32) Cf[(long)(rowb + i) * ldcf + col] = v;
      }
    }
  }
}

template<int BM, int BN, bool RELU, bool HASF32>
__global__ __launch_bounds__(256, 2)
void gemm_bt(const short* __restrict__ A, const short* __restrict__ BT,
             const float* __restrict__ bias,
             short* __restrict__ Cb, int ldcb,
             float* __restrict__ Cf, int ldcf,
             int K, int lda, int ldbt) {
  __shared__ short lds[3 * (BM + BN) * 64];
  gemm_body<BM, BN, RELU, HASF32>(A, BT, bias, Cb, ldcb, Cf, ldcf,
                                  K, lda, ldbt, blockIdx.x * BM, blockIdx.y * BN,
                                  lds);
}

// Fused: encoders (b<512) + W2T GEMM (b<1024) + late-weight transposes
// (Wf [1024,1792), Wc1 [1792,2816), We1 [2816,2832)) + bucket (b==2832).
__global__ __launch_bounds__(256, 2)
void enc_w2t_k(const short* __restrict__ a_bf, const short* __restrict__ v_bf,
               const short* __restrict__ WaT, const short* __restrict__ WvT,
               const float* __restrict__ ba, const float* __restrict__ bv,
               short* __restrict__ afvf, float* __restrict__ out_af,
               float* __restrict__ out_vf,
               const short* __restrict__ WprojT, const short* __restrict__ Watt_rm,
               short* __restrict__ W2T,
               const float* __restrict__ Wf, const float* __restrict__ Wc1,
               const float* __restrict__ We1,
               short* __restrict__ WfT, short* __restrict__ Wc1T,
               short* __restrict__ We1T,
               const int* __restrict__ didx, int* __restrict__ perm,
               int* __restrict__ bstart, int* __restrict__ bmap) {
  __shared__ short lds[3 * (128 + 64) * 64];
  int b = blockIdx.x;
  const int tid = threadIdx.x;
  if (b < 512) {
    const int x = b & 31, y = b >> 5;
    const bool isA = y < 8;
    gemm_body<128, 64, true, true>(
        isA ? a_bf : v_bf, isA ? WaT : WvT, isA ? ba : bv,
        afvf + (isA ? 0 : 512), 1024, isA ? out_af : out_vf, 512,
        isA ? 768 : 2048, isA ? 768 : 2048, isA ? 768 : 2048,
        x << 7, (y & 7) << 6, lds);
  } else if (b < 1024) {
    b -= 512;   // W2T = (Watt @ Wproj)^T : 1024x1024, K=2048, 64x32 tiles
    gemm_body<64, 32, false, false>(
        WprojT, Watt_rm, nullptr, W2T, 1024, nullptr, 0,
        2048, 2048, 2048, (b & 15) << 6, (b >> 4) << 5, lds);
  } else if (b < 2832) {
    b -= 1024;
    const float* in; short* out; int N, ldout, nnb;
    if (b < 768)       { int z = b >> 8; b &= 255;
                         in = Wf + (long)z * 1048576; out = WfT + (long)z * 1048576;
                         N = 1024; ldout = 1024; nnb = 16; }
    else if (b < 1792) { b -= 768; int z = b >> 6; b &= 63;
                         in = Wc1 + (long)z * 262144; out = Wc1T + (long)z * 262144;
                         N = 256; ldout = 1024; nnb = 4; }
    else               { b -= 1792; in = We1; out = We1T; N = 128; ldout = 512; nnb = 2; }
    transpose_tile(in, out, N, ldout, (b % nnb) << 6, (b / nnb) << 6, lds);
  } else {
    // bucketing (alias int scratch onto lds)
    int* cnt = (int*)lds; int* base = cnt + 16; int* curp = base + 17;
    if (tid < 16) cnt[tid] = 0;
    __syncthreads();
    for (int r = tid; r < 4096; r += 256) atomicAdd(&cnt[didx[r]], 1);
    __syncthreads();
    if (tid == 0) {
      int s = 0;
      for (int d = 0; d < 16; ++d) { base[d] = s; s += cnt[d]; }
      base[16] = s;
      int nb = 0;
      for (int d = 0; d < 16; ++d) {
        int nblk = (cnt[d] + 63) >> 6;
        for (int i = 0; i < nblk; ++i) bmap[nb++] = (d << 8) | i;
      }
      bstart[17] = nb;
    }
    __syncthreads();
    if (tid < 16) curp[tid] = base[tid];
    if (tid < 17) bstart[tid] = base[tid];
    __syncthreads();
    for (int r = tid; r < 4096; r += 256) {
      int p = atomicAdd(&curp[didx[r]], 1);
      perm[p] = r;
    }
  }
}

// Fused: G3+4 GEMM (b<512) + emotion layer-1 GEMM (b>=512).
__global__ __launch_bounds__(256, 2)
void g34emo_k(const short* __restrict__ afvf, const short* __restrict__ W2T,
              const float* __restrict__ bproj, short* __restrict__ fusedA,
              const short* __restrict__ We1T, const float* __restrict__ be1,
              short* __restrict__ e1_bf) {
  __shared__ short lds[3 * (128 + 64) * 64];
  int b = blockIdx.x;
  if (b < 512) {
    gemm_body<128, 64, false, false>(
        afvf, W2T, bproj, fusedA, 1024, nullptr, 0,
        1024, 1024, 1024, (b & 31) << 7, (b >> 5) << 6, lds);
  } else {
    b -= 512;   // e1 = relu(vf@We1+be1): 4096x128, K=512, 64x32 tiles
    gemm_body<64, 32, true, false>(
        afvf + 512, We1T, be1, e1_bf, 128, nullptr, 0,
        512, 1024, 512, (b & 63) << 6, (b >> 6) << 5, lds);
  }
}

// ---------------- per-disease head GEMM (gathered rows, pipelined+swizzled) -
__global__ __launch_bounds__(256, 2)
void head_gemm(const short* __restrict__ fused, const short* __restrict__ Wc1T,
               const float* __restrict__ bc1, const int* __restrict__ perm,
               const int* __restrict__ bstart, const int* __restrict__ bmap,
               short* __restrict__ h) {
  const int nb = bstart[17];
  if ((int)blockIdx.x >= nb) return;
  const int me = bmap[blockIdx.x];
  const int d = me >> 8, rt = me & 0xff;
  const int b0 = bstart[d], cnt = bstart[d + 1] - b0;
  const int t0 = rt << 6;
  const int c0 = blockIdx.y << 6;
  __shared__ short lds[3 * 128 * 64];
  const int tid = threadIdx.x, w = tid >> 6, l = tid & 63;
  const int wr = w >> 1, wc = w & 1;
  const int lr = l & 15, lk = (l >> 4) << 3;
  const short* BT = Wc1T + (long)d * (256 * 1024) + (long)c0 * 1024;

  f32x4 acc[2][2];
#pragma unroll
  for (int m = 0; m < 2; ++m)
#pragma unroll
    for (int n = 0; n < 2; ++n) acc[m][n] = (f32x4)0.f;

  const int r_ = tid >> 3;
  const int kc_ = (((tid & 7) ^ (r_ & 7)) << 3);
  int gr0 = (t0 + r_      < cnt) ? perm[b0 + t0 + r_]      : perm[b0];
  int gr1 = (t0 + r_ + 32 < cnt) ? perm[b0 + t0 + r_ + 32] : perm[b0];
  const short* A0 = fused + (long)gr0 * 1024 + kc_;
  const short* A1 = fused + (long)gr1 * 1024 + kc_;
  const short* Brow = BT + (long)r_ * 1024 + kc_;

  auto stage = [&](int t, int buf) {
    const int kt = t << 6;
    char* sA = (char*)lds + buf * 16384;
    char* sB = sA + 8192;
    gload_lds16(A0 + kt, sA + w * 1024);
    gload_lds16(A1 + kt, sA + 4096 + w * 1024);
    gload_lds16(Brow + kt, sB + w * 1024);
    gload_lds16(Brow + 32 * 1024 + kt, sB + 4096 + w * 1024);
  };

  stage(0, 0);
  stage(1, 1);
  int cur = 0;
  for (int t = 0; t < 16; ++t) {
    __builtin_amdgcn_s_barrier();
    __builtin_amdgcn_sched_barrier(0);
    if (t + 2 < 16) {
      int nxt = cur + 2; if (nxt >= 3) nxt -= 3;
      stage(t + 2, nxt);
      waitv<8>();
    } else if (t + 1 < 16) {
      waitv<4>();
    } else {
      waitv<0>();
    }
    __builtin_amdgcn_s_barrier();
    __builtin_amdgcn_sched_barrier(0);
    const short* sA = lds + cur * 8192;
    const short* sB = sA + 4096;
#pragma unroll
    for (int kk = 0; kk < 64; kk += 32) {
      const int cb = (kk + lk) >> 3;
      bf16x8 a[2], b[2];
#pragma unroll
      for (int m = 0; m < 2; ++m) {
        const int ra = wr * 32 + m * 16 + lr;
        a[m] = *(const bf16x8*)&sA[ra * 64 + ((cb ^ (ra & 7)) << 3)];
      }
#pragma unroll
      for (int n = 0; n < 2; ++n) {
        const int rb = wc * 32 + n * 16 + lr;
        b[n] = *(const bf16x8*)&sB[rb * 64 + ((cb ^ (rb & 7)) << 3)];
      }
#pragma unroll
      for (int m = 0; m < 2; ++m)
#pragma unroll
        for (int n = 0; n < 2; ++n)
          acc[m][n] = __builtin_amdgcn_mfma_f32_16x16x32_bf16(a[m], b[n], acc[m][n], 0, 0, 0);
    }
    __builtin_amdgcn_sched_barrier(0);
    cur = (cur == 2) ? 0 : cur + 1;
  }

#pragma unroll
  for (int m = 0; m < 2; ++m)
#pragma unroll
    for (int i2 = 0; i2 < 4; ++i2) {
      const int lrow = wr * 32 + m * 16 + ((l >> 4) << 2) + i2;
      if (t0 + lrow >= cnt) continue;
      const int gr = perm[b0 + t0 + lrow];
#pragma unroll
      for (int n = 0; n < 2; ++n) {
        const int col = c0 + wc * 32 + n * 16 + lr;
        float v = acc[m][n][i2] + bc1[d * 256 + col];
        v = fmaxf(v, 0.f);
        h[(long)gr * 256 + col] = f2b(v);
      }
    }
}

// ---------------- tail: logits GEMV + emotion layer-2 GEMV ----------------
__global__ __launch_bounds__(256)
void tail_k(const short* __restrict__ h, const float* __restrict__ Wc2,
            const float* __restrict__ bc2, const int* __restrict__ didx,
            const short* __restrict__ e1, const float* __restrict__ We2,
            const float* __restrict__ be2,
            float* __restrict__ out_logits, float* __restrict__ out_emo) {
  const int w = threadIdx.x >> 6, l = threadIdx.x & 63;
  if (blockIdx.x < 1024) {
    const int r = ((int)blockIdx.x << 2) + w;
    const int d = didx[r];
    const short4 hv4 = *(const short4*)(h + (long)r * 256 + (l << 2));
    const float* wr_ = Wc2 + d * 512 + (l << 3);
    const float4 w01 = *(const float4*)wr_;
    const float4 w23 = *(const float4*)(wr_ + 4);
    const float h0 = b2f(hv4.x), h1 = b2f(hv4.y), h2 = b2f(hv4.z), h3 = b2f(hv4.w);
    float a0 = h0 * w01.x + h1 * w01.z + h2 * w23.x + h3 * w23.z;
    float a1 = h0 * w01.y + h1 * w01.w + h2 * w23.y + h3 * w23.w;
#pragma unroll
    for (int off = 32; off > 0; off >>= 1) {
      a0 += __shfl_down(a0, off);
      a1 += __shfl_down(a1, off);
    }
    if (l == 0) {
      out_logits[r * 2 + 0] = a0 + bc2[d * 2 + 0];
      out_logits[r * 2 + 1] = a1 + bc2[d * 2 + 1];
    }
  } else {
    const int r = (((int)blockIdx.x - 1024) << 2) + w;
    const float h0 = b2f(e1[(long)r * 128 + 2 * l]);
    const float h1 = b2f(e1[(long)r * 128 + 2 * l + 1]);
    const float* w0 = We2 + (2 * l) * 8;
    float a[8];
#pragma unroll
    for (int c = 0; c < 8; ++c) a[c] = h0 * w0[c] + h1 * w0[8 + c];
#pragma unroll
    for (int c = 0; c < 8; ++c)
#pragma unroll
      for (int off = 32; off > 0; off >>= 1) a[c] += __shfl_down(a[c], off);
    if (l == 0) {
#pragma unroll
      for (int c = 0; c < 8; ++c) out_emo[r * 8 + c] = a[c] + be2[c];
    }
  }
}

// ---------------- launch ----------------
extern "C" void kernel_launch(void* const* d_in, const int* in_sizes, int n_in,
                              void* d_out, int out_size, void* d_ws, size_t ws_size,
                              hipStream_t stream) {
  const float* audio = (const float*)d_in[0];
  const float* video = (const float*)d_in[1];
  const int*   didx  = (const int*)d_in[2];
  const float* Wa    = (const float*)d_in[3];
  const float* ba    = (const float*)d_in[4];
  const float* Wv    = (const float*)d_in[5];
  const float* bv    = (const float*)d_in[6];
  const float* Pa    = (const float*)d_in[7];
  const float* Cva   = (const float*)d_in[8];
  const float* Pv    = (const float*)d_in[9];
  const float* Cav   = (const float*)d_in[10];
  const float* Wproj = (const float*)d_in[11];
  const float* bproj = (const float*)d_in[12];
  const float* Wf    = (const float*)d_in[13];
  const float* bfv   = (const float*)d_in[14];
  const float* Wc1   = (const float*)d_in[15];
  const float* bc1   = (const float*)d_in[16];
  const float* Wc2   = (const float*)d_in[17];
  const float* bc2   = (const float*)d_in[18];
  const float* We1   = (const float*)d_in[19];
  const float* be1   = (const float*)d_in[20];
  const float* We2   = (const float*)d_in[21];
  const float* be2   = (const float*)d_in[22];

  char* ws = (char*)d_ws;
  short* W2T     = (short*)(ws + 0);          // 1024x1024 bf16 = 2MB
  short* WaT     = (short*)(ws + 2097152);
  short* WvT     = (short*)(ws + 2883584);
  short* Watt_rm = (short*)(ws + 4980736);    // 1024x2048 = 4MB
  short* WprojT  = (short*)(ws + 9175040);    // 1024x2048 = 4MB
  short* WfT     = (short*)(ws + 13369344);   // 3x1024x1024 = 6MB
  short* Wc1T    = (short*)(ws + 19660800);   // 16x256x1024 = 8MB
  short* We1T    = (short*)(ws + 28049408);
  short* afvf    = (short*)(ws + 28180480);   // 4096x1024 = 8MB
  short* fusedA  = (short*)(ws + 36569088);   // 8MB
  short* fusedB  = (short*)(ws + 44957696);   // 8MB
  short* h_bf    = (short*)(ws + 53346304);   // 2MB
  short* e1_bf   = (short*)(ws + 55443456);   // 1MB
  int*   perm    = (int*)(ws + 56492032);
  int*   bstart  = (int*)(ws + 56508416);
  int*   bmap    = (int*)(ws + 56508544);
  short* a_bf    = (short*)(ws + 56512512);   // 6MB
  short* v_bf    = (short*)(ws + 62803968);   // 16MB

  float* out        = (float*)d_out;
  float* out_logits = out;
  float* out_af     = out + 8192;
  float* out_vf     = out + 2105344;
  float* out_fused  = out + 4202496;
  float* out_emo    = out + 8396800;

  // enc-stage conversions
  prep_k<<<dim3(4192), dim3(256), 0, stream>>>(
      Wa, Wv, Wproj, Pa, Cva, Cav, Pv, audio, video,
      WaT, WvT, WprojT, Watt_rm, a_bf, v_bf);

  // encoders + W2T + late-weight transposes + bucket (one dispatch)
  enc_w2t_k<<<dim3(2833), dim3(256), 0, stream>>>(
      a_bf, v_bf, WaT, WvT, ba, bv, afvf, out_af, out_vf,
      WprojT, Watt_rm, W2T,
      Wf, Wc1, We1, WfT, Wc1T, We1T,
      didx, perm, bstart, bmap);

  // G3+G4 fused GEMM + emotion layer-1 (independent given afvf)
  g34emo_k<<<dim3(768), dim3(256), 0, stream>>>(
      afvf, W2T, bproj, fusedA, We1T, be1, e1_bf);

  // MLP x3
  gemm_bt<128, 64, true, false><<<dim3(32, 16), dim3(256), 0, stream>>>(
      fusedA, WfT, bfv, fusedB, 1024, nullptr, 0, 1024, 1024, 1024);
  gemm_bt<128, 64, true, false><<<dim3(32, 16), dim3(256), 0, stream>>>(
      fusedB, WfT + 1048576, bfv + 1024, fusedA, 1024, nullptr, 0, 1024, 1024, 1024);
  gemm_bt<128, 64, true, true><<<dim3(32, 16), dim3(256), 0, stream>>>(
      fusedA, WfT + 2097152, bfv + 2048, fusedB, 1024, out_fused, 1024, 1024, 1024, 1024);

  // heads
  head_gemm<<<dim3(80, 4), dim3(256), 0, stream>>>(fusedB, Wc1T, bc1, perm, bstart, bmap, h_bf);
  tail_k<<<dim3(2048), dim3(256), 0, stream>>>(
      h_bf, Wc2, bc2, didx, e1_bf, We2, be2, out_logits, out_emo);
}

// Round 14
// 130.105 us; speedup vs baseline: 1.0351x; 1.0351x over previous
//
#include <hip/hip_runtime.h>
#include <hip/hip_bf16.h>
#include <stdint.h>

// Sizes (fixed): B=4096, A=768, V=2048, H=512, F=1024, ND=16, NC=2, NE=8, NL=3

typedef __attribute__((ext_vector_type(8))) short bf16x8;
typedef __attribute__((ext_vector_type(4))) float f32x4;

__device__ inline short f2b(float f) {
  union { float f; uint32_t u; } a; a.f = f;
  uint32_t r = a.u + 0x7fffu + ((a.u >> 16) & 1u);   // RNE
  return (short)(r >> 16);
}
__device__ inline float b2f(short s) {
  union { uint32_t u; float f; } a; a.u = ((uint32_t)(uint16_t)s) << 16;
  return a.f;
}
__device__ inline void gload_lds16(const void* g, void* l) {
  __builtin_amdgcn_global_load_lds(
      (const __attribute__((address_space(1))) uint32_t*)g,
      (__attribute__((address_space(3))) uint32_t*)l, 16, 0, 0);
}
template<int N> __device__ __forceinline__ void waitv() {
  asm volatile("s_waitcnt vmcnt(%0)" :: "n"(N) : "memory");
}

// 64x64 f32->bf16 transpose tile via LDS scratch (needs >= 64*66 shorts).
__device__ __forceinline__
void transpose_tile(const float* __restrict__ in, short* __restrict__ out,
                    int N, int ldout, int n0, int k0, short* scratch) {
  short (*t)[66] = (short(*)[66])scratch;
  const int tid = threadIdx.x;
#pragma unroll
  for (int p = 0; p < 4; ++p) {
    const int item = p * 256 + tid;
    const int row = item >> 4, c4 = (item & 15) << 2;
    float4 v = *(const float4*)(in + (long)(k0 + row) * N + n0 + c4);
    short4 o; o.x = f2b(v.x); o.y = f2b(v.y); o.z = f2b(v.z); o.w = f2b(v.w);
    *(short4*)&t[row][c4] = o;
  }
  __syncthreads();
#pragma unroll
  for (int p = 0; p < 4; ++p) {
    const int item = p * 256 + tid;
    const int kg4 = item & 15, n = item >> 4;
    short4 o;
    o.x = t[4 * kg4 + 0][n]; o.y = t[4 * kg4 + 1][n];
    o.z = t[4 * kg4 + 2][n]; o.w = t[4 * kg4 + 3][n];
    *(short4*)(out + (long)(n0 + n) * ldout + k0 + 4 * kg4) = o;
  }
}

// ---------------- prep kernel: enc-stage deps only ----------------
// [0,96) Wa  [96,352) Wv  [352,864) Wproj  [864,1376) Watt_rm
// [1376,2144) audio conv  [2144,4192) video conv
__global__ __launch_bounds__(256)
void prep_k(const float* __restrict__ Wa, const float* __restrict__ Wv,
            const float* __restrict__ Wproj,
            const float* __restrict__ Pa, const float* __restrict__ Cva,
            const float* __restrict__ Cav, const float* __restrict__ Pv,
            const float* __restrict__ audio, const float* __restrict__ video,
            short* __restrict__ WaT, short* __restrict__ WvT,
            short* __restrict__ WprojT, short* __restrict__ Watt,
            short* __restrict__ a_bf, short* __restrict__ v_bf) {
  __shared__ short t[64 * 66];
  int b = blockIdx.x;
  const int tid = threadIdx.x;

  if (b >= 1376) {                    // input conversions, 4096 elems/block
    const float* in; short* out;
    if (b < 2144) { b -= 1376; in = audio; out = a_bf; }
    else          { b -= 2144; in = video; out = v_bf; }
    const long base_ = (long)b * 4096;
#pragma unroll
    for (int p = 0; p < 4; ++p) {
      const long i = base_ + ((p * 256 + tid) << 2);
      float4 v = *(const float4*)(in + i);
      short4 o; o.x = f2b(v.x); o.y = f2b(v.y); o.z = f2b(v.z); o.w = f2b(v.w);
      *(short4*)(out + i) = o;
    }
    return;
  }
  if (b >= 864) {                     // Watt_rm quadrants, 4 rows/block
    b -= 864;
    const int q = b >> 7, r4 = (b & 127) << 2;
    const float* src; int rowoff, coloff;
    if (q == 0)      { src = Pa;  rowoff = 0;   coloff = 0; }
    else if (q == 1) { src = Cav; rowoff = 0;   coloff = 1024; }
    else if (q == 2) { src = Cva; rowoff = 512; coloff = 0; }
    else             { src = Pv;  rowoff = 512; coloff = 1024; }
#pragma unroll
    for (int p = 0; p < 4; ++p) {
      const int item = p * 256 + tid;
      const int h = r4 + (item >> 8), j = (item & 255) << 2;
      float4 v = *(const float4*)(src + (long)h * 1024 + j);
      short4 o; o.x = f2b(v.x); o.y = f2b(v.y); o.z = f2b(v.z); o.w = f2b(v.w);
      *(short4*)(Watt + (long)(rowoff + h) * 2048 + coloff + j) = o;
    }
    return;
  }
  const float* in; short* out; int N, ldout, nnb;
  if (b < 96)       { in = Wa;    out = WaT;    N = 512;  ldout = 768;  nnb = 8; }
  else if (b < 352) { b -= 96;  in = Wv;    out = WvT;    N = 512;  ldout = 2048; nnb = 8; }
  else              { b -= 352; in = Wproj; out = WprojT; N = 1024; ldout = 2048; nnb = 16; }
  transpose_tile(in, out, N, ldout, (b % nnb) << 6, (b / nnb) << 6, t);
}

// ---------------- GEMM body: depth-1 prefetch + T2 XOR swizzle -------------
// C = A(MxK, bf16) * BT(NxK, bf16)^T. 4 waves (2x2); BK=64; 16x16x32 MFMA.
// 2 LDS buffers (48KB at 128x64 -> 3 blocks/CU); per step:
//   barrier / stage(t+1, cur^1) / vmcnt(S) / barrier / MFMA(t).
// Swizzle (rule #21): linear LDS dest; global source col-group pre-permuted
// (c8 = (tid&7) ^ (row&7)); reads XOR the same way.
template<int BM, int BN, bool RELU, bool HASF32>
__device__ __forceinline__
void gemm_body(const short* __restrict__ A, const short* __restrict__ BT,
               const float* __restrict__ bias,
               short* __restrict__ Cb, int ldcb,
               float* __restrict__ Cf, int ldcf,
               int K, int lda, int ldbt, int m0, int n0,
               short* lds) {
  constexpr int MR = BM / 32, NR = BN / 32;
  constexpr int S = MR + NR;                 // gload_lds per wave per tile
  constexpr int BUF = (BM + BN) * 64;        // shorts per buffer
  const int tid = threadIdx.x;
  const int w = tid >> 6, l = tid & 63;
  const int wr = w >> 1, wc = w & 1;
  const int lr = l & 15, lk = (l >> 4) << 3;

  f32x4 acc[MR][NR];
#pragma unroll
  for (int m = 0; m < MR; ++m)
#pragma unroll
    for (int n = 0; n < NR; ++n) acc[m][n] = (f32x4)0.f;

  const int r_ = tid >> 3;            // 0..31
  const int kc_ = (((tid & 7) ^ (r_ & 7)) << 3);   // swizzled source col-group
  const short* Arow = A + (long)(m0 + r_) * lda + kc_;
  const short* Brow = BT + (long)(n0 + r_) * ldbt + kc_;
  const int nk = K >> 6;

  auto stage = [&](int t, int buf) {
    const int kt = t << 6;
    char* sA = (char*)(lds + buf * BUF);
    char* sB = sA + BM * 128;
#pragma unroll
    for (int i = 0; i < MR; ++i)
      gload_lds16(Arow + (long)i * 32 * lda + kt, sA + i * 4096 + w * 1024);
#pragma unroll
    for (int i = 0; i < NR; ++i)
      gload_lds16(Brow + (long)i * 32 * ldbt + kt, sB + i * 4096 + w * 1024);
  };

  stage(0, 0);
  int cur = 0;
  for (int t = 0; t < nk; ++t) {
    __builtin_amdgcn_s_barrier();            // waves done reading buf cur^1
    __builtin_amdgcn_sched_barrier(0);
    if (t + 1 < nk) {
      stage(t + 1, cur ^ 1);
      waitv<S>();                            // tile t's loads complete
    } else {
      waitv<0>();
    }
    __builtin_amdgcn_s_barrier();            // tile t visible to all waves
    __builtin_amdgcn_sched_barrier(0);
    const short* sA = lds + cur * BUF;
    const short* sB = sA + BM * 64;
#pragma unroll
    for (int kk = 0; kk < 64; kk += 32) {
      const int cb = (kk + lk) >> 3;
      bf16x8 a[MR], b[NR];
#pragma unroll
      for (int m = 0; m < MR; ++m) {
        const int ra = wr * (BM / 2) + m * 16 + lr;
        a[m] = *(const bf16x8*)&sA[ra * 64 + ((cb ^ (ra & 7)) << 3)];
      }
#pragma unroll
      for (int n = 0; n < NR; ++n) {
        const int rb = wc * (BN / 2) + n * 16 + lr;
        b[n] = *(const bf16x8*)&sB[rb * 64 + ((cb ^ (rb & 7)) << 3)];
      }
#pragma unroll
      for (int m = 0; m < MR; ++m)
#pragma unroll
        for (int n = 0; n < NR; ++n)
          acc[m][n] = __builtin_amdgcn_mfma_f32_16x16x32_bf16(a[m], b[n], acc[m][n], 0, 0, 0);
    }
    __builtin_amdgcn_sched_barrier(0);
    cur ^= 1;
  }

  const int lrow = (l >> 4) << 2;
#pragma unroll
  for (int n = 0; n < NR; ++n) {
    const int col = n0 + wc * (BN / 2) + n * 16 + lr;
    const float bz = bias ? bias[col] : 0.f;
#pragma unroll
    for (int m = 0; m < MR; ++m) {
      const int rowb = m0 + wr * (BM / 2) + m * 16 + lrow;
#pragma unroll
      for (int i = 0; i < 4; ++i) {
        float v = acc[m][n][i] + bz;
        if (RELU) v = fmaxf(v, 0.f);
        Cb[(long)(rowb + i) * ldcb + col] = f2b(v);
        if (HASF32) Cf[(long)(rowb + i) * ldcf + col] = v;
      }
    }
  }
}

template<int BM, int BN, bool RELU, bool HASF32>
__global__ __launch_bounds__(256, 3)
void gemm_bt(const short* __restrict__ A, const short* __restrict__ BT,
             const float* __restrict__ bias,
             short* __restrict__ Cb, int ldcb,
             float* __restrict__ Cf, int ldcf,
             int K, int lda, int ldbt) {
  __shared__ short lds[2 * (BM + BN) * 64];
  gemm_body<BM, BN, RELU, HASF32>(A, BT, bias, Cb, ldcb, Cf, ldcf,
                                  K, lda, ldbt, blockIdx.x * BM, blockIdx.y * BN,
                                  lds);
}

// Fused: encoders (b<512) + W2T GEMM (b<1024) + late-weight transposes
// (Wf [1024,1792), Wc1 [1792,2816), We1 [2816,2832)) + bucket (b==2832).
__global__ __launch_bounds__(256, 3)
void enc_w2t_k(const short* __restrict__ a_bf, const short* __restrict__ v_bf,
               const short* __restrict__ WaT, const short* __restrict__ WvT,
               const float* __restrict__ ba, const float* __restrict__ bv,
               short* __restrict__ afvf, float* __restrict__ out_af,
               float* __restrict__ out_vf,
               const short* __restrict__ WprojT, const short* __restrict__ Watt_rm,
               short* __restrict__ W2T,
               const float* __restrict__ Wf, const float* __restrict__ Wc1,
               const float* __restrict__ We1,
               short* __restrict__ WfT, short* __restrict__ Wc1T,
               short* __restrict__ We1T,
               const int* __restrict__ didx, int* __restrict__ perm,
               int* __restrict__ bstart, int* __restrict__ bmap) {
  __shared__ short lds[2 * (128 + 64) * 64];
  int b = blockIdx.x;
  const int tid = threadIdx.x;
  if (b < 512) {
    const int x = b & 31, y = b >> 5;
    const bool isA = y < 8;
    gemm_body<128, 64, true, true>(
        isA ? a_bf : v_bf, isA ? WaT : WvT, isA ? ba : bv,
        afvf + (isA ? 0 : 512), 1024, isA ? out_af : out_vf, 512,
        isA ? 768 : 2048, isA ? 768 : 2048, isA ? 768 : 2048,
        x << 7, (y & 7) << 6, lds);
  } else if (b < 1024) {
    b -= 512;   // W2T = (Watt @ Wproj)^T : 1024x1024, K=2048, 64x32 tiles
    gemm_body<64, 32, false, false>(
        WprojT, Watt_rm, nullptr, W2T, 1024, nullptr, 0,
        2048, 2048, 2048, (b & 15) << 6, (b >> 4) << 5, lds);
  } else if (b < 2832) {
    b -= 1024;
    const float* in; short* out; int N, ldout, nnb;
    if (b < 768)       { int z = b >> 8; b &= 255;
                         in = Wf + (long)z * 1048576; out = WfT + (long)z * 1048576;
                         N = 1024; ldout = 1024; nnb = 16; }
    else if (b < 1792) { b -= 768; int z = b >> 6; b &= 63;
                         in = Wc1 + (long)z * 262144; out = Wc1T + (long)z * 262144;
                         N = 256; ldout = 1024; nnb = 4; }
    else               { b -= 1792; in = We1; out = We1T; N = 128; ldout = 512; nnb = 2; }
    transpose_tile(in, out, N, ldout, (b % nnb) << 6, (b / nnb) << 6, lds);
  } else {
    // bucketing (alias int scratch onto lds)
    int* cnt = (int*)lds; int* base = cnt + 16; int* curp = base + 17;
    if (tid < 16) cnt[tid] = 0;
    __syncthreads();
    for (int r = tid; r < 4096; r += 256) atomicAdd(&cnt[didx[r]], 1);
    __syncthreads();
    if (tid == 0) {
      int s = 0;
      for (int d = 0; d < 16; ++d) { base[d] = s; s += cnt[d]; }
      base[16] = s;
      int nb = 0;
      for (int d = 0; d < 16; ++d) {
        int nblk = (cnt[d] + 63) >> 6;
        for (int i = 0; i < nblk; ++i) bmap[nb++] = (d << 8) | i;
      }
      bstart[17] = nb;
    }
    __syncthreads();
    if (tid < 16) curp[tid] = base[tid];
    if (tid < 17) bstart[tid] = base[tid];
    __syncthreads();
    for (int r = tid; r < 4096; r += 256) {
      int p = atomicAdd(&curp[didx[r]], 1);
      perm[p] = r;
    }
  }
}

// Fused: G3+4 GEMM (b<512) + emotion layer-1 GEMM (b>=512).
__global__ __launch_bounds__(256, 3)
void g34emo_k(const short* __restrict__ afvf, const short* __restrict__ W2T,
              const float* __restrict__ bproj, short* __restrict__ fusedA,
              const short* __restrict__ We1T, const float* __restrict__ be1,
              short* __restrict__ e1_bf) {
  __shared__ short lds[2 * (128 + 64) * 64];
  int b = blockIdx.x;
  if (b < 512) {
    gemm_body<128, 64, false, false>(
        afvf, W2T, bproj, fusedA, 1024, nullptr, 0,
        1024, 1024, 1024, (b & 31) << 7, (b >> 5) << 6, lds);
  } else {
    b -= 512;   // e1 = relu(vf@We1+be1): 4096x128, K=512, 64x32 tiles
    gemm_body<64, 32, true, false>(
        afvf + 512, We1T, be1, e1_bf, 128, nullptr, 0,
        512, 1024, 512, (b & 63) << 6, (b >> 6) << 5, lds);
  }
}

// ---------------- per-disease head GEMM (gathered rows, depth-1+swizzled) ---
__global__ __launch_bounds__(256, 3)
void head_gemm(const short* __restrict__ fused, const short* __restrict__ Wc1T,
               const float* __restrict__ bc1, const int* __restrict__ perm,
               const int* __restrict__ bstart, const int* __restrict__ bmap,
               short* __restrict__ h) {
  const int nb = bstart[17];
  if ((int)blockIdx.x >= nb) return;
  const int me = bmap[blockIdx.x];
  const int d = me >> 8, rt = me & 0xff;
  const int b0 = bstart[d], cnt = bstart[d + 1] - b0;
  const int t0 = rt << 6;
  const int c0 = blockIdx.y << 6;
  __shared__ short lds[2 * 128 * 64];        // 2 bufs x (64A+64B) x 64
  const int tid = threadIdx.x, w = tid >> 6, l = tid & 63;
  const int wr = w >> 1, wc = w & 1;
  const int lr = l & 15, lk = (l >> 4) << 3;
  const short* BT = Wc1T + (long)d * (256 * 1024) + (long)c0 * 1024;

  f32x4 acc[2][2];
#pragma unroll
  for (int m = 0; m < 2; ++m)
#pragma unroll
    for (int n = 0; n < 2; ++n) acc[m][n] = (f32x4)0.f;

  const int r_ = tid >> 3;
  const int kc_ = (((tid & 7) ^ (r_ & 7)) << 3);
  int gr0 = (t0 + r_      < cnt) ? perm[b0 + t0 + r_]      : perm[b0];
  int gr1 = (t0 + r_ + 32 < cnt) ? perm[b0 + t0 + r_ + 32] : perm[b0];
  const short* A0 = fused + (long)gr0 * 1024 + kc_;
  const short* A1 = fused + (long)gr1 * 1024 + kc_;
  const short* Brow = BT + (long)r_ * 1024 + kc_;

  auto stage = [&](int t, int buf) {
    const int kt = t << 6;
    char* sA = (char*)lds + buf * 16384;
    char* sB = sA + 8192;
    gload_lds16(A0 + kt, sA + w * 1024);
    gload_lds16(A1 + kt, sA + 4096 + w * 1024);
    gload_lds16(Brow + kt, sB + w * 1024);
    gload_lds16(Brow + 32 * 1024 + kt, sB + 4096 + w * 1024);
  };

  stage(0, 0);
  int cur = 0;
  for (int t = 0; t < 16; ++t) {
    __builtin_amdgcn_s_barrier();
    __builtin_amdgcn_sched_barrier(0);
    if (t + 1 < 16) {
      stage(t + 1, cur ^ 1);
      waitv<4>();
    } else {
      waitv<0>();
    }
    __builtin_amdgcn_s_barrier();
    __builtin_amdgcn_sched_barrier(0);
    const short* sA = lds + cur * 8192;
    const short* sB = sA + 4096;
#pragma unroll
    for (int kk = 0; kk < 64; kk += 32) {
      const int cb = (kk + lk) >> 3;
      bf16x8 a[2], b[2];
#pragma unroll
      for (int m = 0; m < 2; ++m) {
        const int ra = wr * 32 + m * 16 + lr;
        a[m] = *(const bf16x8*)&sA[ra * 64 + ((cb ^ (ra & 7)) << 3)];
      }
#pragma unroll
      for (int n = 0; n < 2; ++n) {
        const int rb = wc * 32 + n * 16 + lr;
        b[n] = *(const bf16x8*)&sB[rb * 64 + ((cb ^ (rb & 7)) << 3)];
      }
#pragma unroll
      for (int m = 0; m < 2; ++m)
#pragma unroll
        for (int n = 0; n < 2; ++n)
          acc[m][n] = __builtin_amdgcn_mfma_f32_16x16x32_bf16(a[m], b[n], acc[m][n], 0, 0, 0);
    }
    __builtin_amdgcn_sched_barrier(0);
    cur ^= 1;
  }

#pragma unroll
  for (int m = 0; m < 2; ++m)
#pragma unroll
    for (int i2 = 0; i2 < 4; ++i2) {
      const int lrow = wr * 32 + m * 16 + ((l >> 4) << 2) + i2;
      if (t0 + lrow >= cnt) continue;
      const int gr = perm[b0 + t0 + lrow];
#pragma unroll
      for (int n = 0; n < 2; ++n) {
        const int col = c0 + wc * 32 + n * 16 + lr;
        float v = acc[m][n][i2] + bc1[d * 256 + col];
        v = fmaxf(v, 0.f);
        h[(long)gr * 256 + col] = f2b(v);
      }
    }
}

// ---------------- tail: logits GEMV + emotion layer-2 GEMV ----------------
__global__ __launch_bounds__(256)
void tail_k(const short* __restrict__ h, const float* __restrict__ Wc2,
            const float* __restrict__ bc2, const int* __restrict__ didx,
            const short* __restrict__ e1, const float* __restrict__ We2,
            const float* __restrict__ be2,
            float* __restrict__ out_logits, float* __restrict__ out_emo) {
  const int w = threadIdx.x >> 6, l = threadIdx.x & 63;
  if (blockIdx.x < 1024) {
    const int r = ((int)blockIdx.x << 2) + w;
    const int d = didx[r];
    const short4 hv4 = *(const short4*)(h + (long)r * 256 + (l << 2));
    const float* wr_ = Wc2 + d * 512 + (l << 3);
    const float4 w01 = *(const float4*)wr_;
    const float4 w23 = *(const float4*)(wr_ + 4);
    const float h0 = b2f(hv4.x), h1 = b2f(hv4.y), h2 = b2f(hv4.z), h3 = b2f(hv4.w);
    float a0 = h0 * w01.x + h1 * w01.z + h2 * w23.x + h3 * w23.z;
    float a1 = h0 * w01.y + h1 * w01.w + h2 * w23.y + h3 * w23.w;
#pragma unroll
    for (int off = 32; off > 0; off >>= 1) {
      a0 += __shfl_down(a0, off);
      a1 += __shfl_down(a1, off);
    }
    if (l == 0) {
      out_logits[r * 2 + 0] = a0 + bc2[d * 2 + 0];
      out_logits[r * 2 + 1] = a1 + bc2[d * 2 + 1];
    }
  } else {
    const int r = (((int)blockIdx.x - 1024) << 2) + w;
    const float h0 = b2f(e1[(long)r * 128 + 2 * l]);
    const float h1 = b2f(e1[(long)r * 128 + 2 * l + 1]);
    const float* w0 = We2 + (2 * l) * 8;
    float a[8];
#pragma unroll
    for (int c = 0; c < 8; ++c) a[c] = h0 * w0[c] + h1 * w0[8 + c];
#pragma unroll
    for (int c = 0; c < 8; ++c)
#pragma unroll
      for (int off = 32; off > 0; off >>= 1) a[c] += __shfl_down(a[c], off);
    if (l == 0) {
#pragma unroll
      for (int c = 0; c < 8; ++c) out_emo[r * 8 + c] = a[c] + be2[c];
    }
  }
}

// ---------------- launch ----------------
extern "C" void kernel_launch(void* const* d_in, const int* in_sizes, int n_in,
                              void* d_out, int out_size, void* d_ws, size_t ws_size,
                              hipStream_t stream) {
  const float* audio = (const float*)d_in[0];
  const float* video = (const float*)d_in[1];
  const int*   didx  = (const int*)d_in[2];
  const float* Wa    = (const float*)d_in[3];
  const float* ba    = (const float*)d_in[4];
  const float* Wv    = (const float*)d_in[5];
  const float* bv    = (const float*)d_in[6];
  const float* Pa    = (const float*)d_in[7];
  const float* Cva   = (const float*)d_in[8];
  const float* Pv    = (const float*)d_in[9];
  const float* Cav   = (const float*)d_in[10];
  const float* Wproj = (const float*)d_in[11];
  const float* bproj = (const float*)d_in[12];
  const float* Wf    = (const float*)d_in[13];
  const float* bfv   = (const float*)d_in[14];
  const float* Wc1   = (const float*)d_in[15];
  const float* bc1   = (const float*)d_in[16];
  const float* Wc2   = (const float*)d_in[17];
  const float* bc2   = (const float*)d_in[18];
  const float* We1   = (const float*)d_in[19];
  const float* be1   = (const float*)d_in[20];
  const float* We2   = (const float*)d_in[21];
  const float* be2   = (const float*)d_in[22];

  char* ws = (char*)d_ws;
  short* W2T     = (short*)(ws + 0);          // 1024x1024 bf16 = 2MB
  short* WaT     = (short*)(ws + 2097152);
  short* WvT     = (short*)(ws + 2883584);
  short* Watt_rm = (short*)(ws + 4980736);    // 1024x2048 = 4MB
  short* WprojT  = (short*)(ws + 9175040);    // 1024x2048 = 4MB
  short* WfT     = (short*)(ws + 13369344);   // 3x1024x1024 = 6MB
  short* Wc1T    = (short*)(ws + 19660800);   // 16x256x1024 = 8MB
  short* We1T    = (short*)(ws + 28049408);
  short* afvf    = (short*)(ws + 28180480);   // 4096x1024 = 8MB
  short* fusedA  = (short*)(ws + 36569088);   // 8MB
  short* fusedB  = (short*)(ws + 44957696);   // 8MB
  short* h_bf    = (short*)(ws + 53346304);   // 2MB
  short* e1_bf   = (short*)(ws + 55443456);   // 1MB
  int*   perm    = (int*)(ws + 56492032);
  int*   bstart  = (int*)(ws + 56508416);
  int*   bmap    = (int*)(ws + 56508544);
  short* a_bf    = (short*)(ws + 56512512);   // 6MB
  short* v_bf    = (short*)(ws + 62803968);   // 16MB

  float* out        = (float*)d_out;
  float* out_logits = out;
  float* out_af     = out + 8192;
  float* out_vf     = out + 2105344;
  float* out_fused  = out + 4202496;
  float* out_emo    = out + 8396800;

  // enc-stage conversions
  prep_k<<<dim3(4192), dim3(256), 0, stream>>>(
      Wa, Wv, Wproj, Pa, Cva, Cav, Pv, audio, video,
      WaT, WvT, WprojT, Watt_rm, a_bf, v_bf);

  // encoders + W2T + late-weight transposes + bucket (one dispatch)
  enc_w2t_k<<<dim3(2833), dim3(256), 0, stream>>>(
      a_bf, v_bf, WaT, WvT, ba, bv, afvf, out_af, out_vf,
      WprojT, Watt_rm, W2T,
      Wf, Wc1, We1, WfT, Wc1T, We1T,
      didx, perm, bstart, bmap);

  // G3+G4 fused GEMM + emotion layer-1 (independent given afvf)
  g34emo_k<<<dim3(768), dim3(256), 0, stream>>>(
      afvf, W2T, bproj, fusedA, We1T, be1, e1_bf);

  // MLP x3
  gemm_bt<128, 64, true, false><<<dim3(32, 16), dim3(256), 0, stream>>>(
      fusedA, WfT, bfv, fusedB, 1024, nullptr, 0, 1024, 1024, 1024);
  gemm_bt<128, 64, true, false><<<dim3(32, 16), dim3(256), 0, stream>>>(
      fusedB, WfT + 1048576, bfv + 1024, fusedA, 1024, nullptr, 0, 1024, 1024, 1024);
  gemm_bt<128, 64, true, true><<<dim3(32, 16), dim3(256), 0, stream>>>(
      fusedA, WfT + 2097152, bfv + 2048, fusedB, 1024, out_fused, 1024, 1024, 1024, 1024);

  // heads
  head_gemm<<<dim3(80, 4), dim3(256), 0, stream>>>(fusedB, Wc1T, bc1, perm, bstart, bmap, h_bf);
  tail_k<<<dim3(2048), dim3(256), 0, stream>>>(
      h_bf, Wc2, bc2, didx, e1_bf, We2, be2, out_logits, out_emo);
}